// Round 22
// baseline (25.395 us; speedup 1.0000x reference)
//
#include <hip/hip_runtime.h>

#define E  9
#define B_ 8
#define H_ 224
#define W_ 224
#define C_ 32
#define TH 7                        // rows per thread
#define TW 2                        // w pixels per thread
#define WT 16                       // w pixels per block (8 w-pairs x 32 ch)
#define STRIPS (H_ / TH)            // 32
#define WTILES (W_ / WT)            // 14
#define NBLK (B_ * STRIPS * WTILES) // 3584 = 14 blocks/CU, %8==0

__global__ __launch_bounds__(256) void fm_main(const float* __restrict__ inp,
                                               const float* __restrict__ kern,
                                               const float* __restrict__ mask,
                                               float* __restrict__ out) {
    int t = threadIdx.x;

    // Bijective XCD-chunk swizzle (448 blocks per XCD).
    int bid = blockIdx.x;
    int swz = (bid & 7) * (NBLK / 8) + (bid >> 3);
    int bw  = swz % WTILES;
    int t2  = swz / WTILES;
    int hs  = (t2 % STRIPS) * TH;   // strip start row
    int b   = t2 / STRIPS;

    int c  = t & 31;                // channel (lane-contiguous -> coalesced)
    int wg = t >> 5;                // 0..7 -> w-pair
    int w0 = bw * WT + wg * TW;     // first of 2 owned w positions

    const float* base = inp + (((size_t)b * H_ * W_ + w0) * C_) + c;
    bool wm = (w0 > 0);             // col w0-1 exists
    bool wp = (w0 + TW < W_);       // col w0+2 exists

    // ---- Tap prologue: (TH+2) x (TW+2) taps -> registers.
    // Best measured config (R17, 25.09us): e-outer coeff streaming fixed the
    // per-row coeff redelivery plateau; TW=2 amortizes the x-halo at a live
    // set (~82 regs) the allocator will actually keep resident.
    float tap[TH + 2][TW + 2];
#pragma unroll
    for (int r = 0; r < TH + 2; ++r) {
        int hh = hs - 1 + r;
        if ((unsigned)hh < (unsigned)H_) {   // block-uniform branch
            const float* p = base + (size_t)hh * (W_ * C_);
            tap[r][0] = wm ? p[-C_] : 0.f;
            tap[r][1] = p[0];
            tap[r][2] = p[C_];               // w0+1 always < W_ (output col)
            tap[r][3] = wp ? p[2 * C_] : 0.f;
        } else {
#pragma unroll
            for (int j = 0; j < TW + 2; ++j) tap[r][j] = 0.f;
        }
    }

    // ---- absmax(|mask|): lanes 0..31 cover all 32 channels.
    float mv[E];
    float mx = 0.f;
#pragma unroll
    for (int e = 0; e < E; ++e) {
        mv[e] = fabsf(mask[e * C_ + c]);
        mx = fmaxf(mx, mv[e]);
    }
    mx = fmaxf(mx, __shfl_xor(mx, 1));
    mx = fmaxf(mx, __shfl_xor(mx, 2));
    mx = fmaxf(mx, __shfl_xor(mx, 4));
    mx = fmaxf(mx, __shfl_xor(mx, 8));
    mx = fmaxf(mx, __shfl_xor(mx, 16));
    float inv = 1.f / (mx + 1e-6f);

    float cm[E], ck[E];
#pragma unroll
    for (int e = 0; e < E; ++e) {
        cm[e] = mv[e] * inv;
        ck[e] = kern[e * C_ + c];
    }

    // tap order: e=0 center, then (y,x) raster skipping center
    const int dyA[E] = {0, -1, -1, -1, 0, 0, 1, 1, 1};
    const int dxA[E] = {0, -1,  0,  1, -1, 1, -1, 0, 1};

    const float inv9 = 1.f / 9.f;

    float n[TH][TW], sm[TH][TW];
#pragma unroll
    for (int s = 0; s < TH; ++s)
#pragma unroll
        for (int j = 0; j < TW; ++j) { n[s][j] = 0.f; sm[s][j] = 0.f; }

    // ---- Pass 1: e-outer, accumulate n and sum (no d storage).
#pragma unroll
    for (int e = 0; e < E; ++e) {
        float m = cm[e], k = ck[e];
#pragma unroll
        for (int s = 0; s < TH; ++s) {
#pragma unroll
            for (int j = 0; j < TW; ++j) {
                float d0 = fmaf(tap[s + 1 + dyA[e]][1 + j + dxA[e]], m, -k);
                n[s][j]  += fabsf(d0);   // abs as src modifier
                sm[s][j] += d0;
            }
        }
    }

    // ---- Pass 2: recompute d from resident taps; finalize and store.
#pragma unroll
    for (int s = 0; s < TH; ++s) {
        float nm0 = sm[s][0] * (-inv9);
        float nm1 = sm[s][1] * (-inv9);
        float v0 = 0.f, v1 = 0.f;
#pragma unroll
        for (int e = 0; e < E; ++e) {
            float d0 = fmaf(tap[s + 1 + dyA[e]][1 + dxA[e]],     cm[e], -ck[e]);
            float d1 = fmaf(tap[s + 1 + dyA[e]][2 + dxA[e]],     cm[e], -ck[e]);
            v0 += fabsf(fabsf(d0) + nm0);
            v1 += fabsf(fabsf(d1) + nm1);
        }

        float o0 = fmaf(v0, -inv9, 1.f) * fmaf(n[s][0], -inv9, 1.f);
        float o1 = fmaf(v1, -inv9, 1.f) * fmaf(n[s][1], -inv9, 1.f);

        // write-once/never-read: non-temporal bypasses L2/L3
        float* op = out + (((size_t)b * H_ + (hs + s)) * W_ + w0) * C_ + c;
        __builtin_nontemporal_store(o0, op);
        __builtin_nontemporal_store(o1, op + C_);
    }
}

extern "C" void kernel_launch(void* const* d_in, const int* in_sizes, int n_in,
                              void* d_out, int out_size, void* d_ws, size_t ws_size,
                              hipStream_t stream) {
    const float* inp  = (const float*)d_in[0];
    const float* kern = (const float*)d_in[1];
    const float* mask = (const float*)d_in[2];
    float* out = (float*)d_out;

    fm_main<<<NBLK, 256, 0, stream>>>(inp, kern, mask, out);
}